// Round 23
// baseline (142.350 us; speedup 1.0000x reference)
//
#include <hip/hip_runtime.h>
#include <math.h>

#define XD 48
#define YD 48
#define ZD 48
#define CD 64
#define NGT 10
#define NB 2
#define KP 128
#define MVOX (XD*YD*ZD)   // 110592
#define ANCH 12.0f
#define BLK_PER_BATCH 432 // MVOX/256

#define NBIN 2048
#define CANDCAP 4096
#define NSLICE 32

typedef float v2f __attribute__((ext_vector_type(2)));

__device__ __forceinline__ unsigned pjbin(unsigned pbits) {
  unsigned d = 0x3F800000u - pbits;
  if (d == 0u) return 2047u;
  int msb = 31 - __clz(d);
  unsigned frac = (msb >= 6) ? ((d >> (msb - 6)) & 63u) : ((d << (6 - msb)) & 63u);
  unsigned bin = ((unsigned)msb << 6) | frac;
  return 2047u - bin;
}

__device__ __forceinline__ unsigned long long shfl_u64(unsigned long long v, int src) {
  int lo = __shfl((int)(unsigned)(v & 0xffffffffull), src);
  int hi = __shfl((int)(unsigned)(v >> 32), src);
  return ((unsigned long long)(unsigned)hi << 32) | (unsigned)lo;
}

// ---------------- conv: channel-0 (logit) only; block covers 4 z-planes for L1 halo reuse ----------------
// block 384 = (8 xseg) x (12 y) x (4 z); grid (12, 4, NB*G)
template<int CPG>
__global__ __launch_bounds__(384) void conv_kernel(const float* __restrict__ feat_zyx,
                                                   const float* __restrict__ Wt,
                                                   float* __restrict__ pred0,
                                                   unsigned* __restrict__ zeroBuf,
                                                   int zeroN) {
  const int t = threadIdx.x;
  const int q = t & 7;                    // x-segment 0..7
  const int yloc = (t >> 3) % 12;
  const int zloc = (t >> 3) / 12;         // 0..3
  const int y = blockIdx.y*12 + yloc;
  const int z = blockIdx.x*4 + zloc;
  const int cg = blockIdx.z >> 1;
  const int b  = blockIdx.z & 1;
  const int c0 = cg * CPG;
  const int x0 = q * 6;

  if (blockIdx.x == 0 && blockIdx.y == 0 && blockIdx.z == 0)
    for (int i = t; i < zeroN; i += 384) zeroBuf[i] = 0u;

  v2f acc[3];
  #pragma unroll
  for (int j = 0; j < 3; ++j) acc[j] = (v2f){0.f, 0.f};

  const float* fb = feat_zyx + ((size_t)b*CD + c0) * MVOX;
  for (int cc = 0; cc < CPG; ++cc) {
    const float* fc = fb + (size_t)cc * MVOX;
    const float* Wc = Wt + (c0 + cc) * 27;
    #pragma unroll
    for (int dz = -1; dz <= 1; ++dz) {
      const int zz = z + dz;
      if (zz < 0 || zz >= ZD) continue;
      #pragma unroll
      for (int dy = -1; dy <= 1; ++dy) {
        const int yy = y + dy;
        const bool vrow = (yy >= 0 && yy < YD);
        const float* rp = fc + (zz*YD + (vrow ? yy : 0))*XD + x0;
        float2 p01 = *(const float2*)(rp);
        float2 p23 = *(const float2*)(rp + 2);
        float2 p45 = *(const float2*)(rp + 4);
        const float e1 = vrow ? p01.x : 0.f, e2 = vrow ? p01.y : 0.f;
        const float e3 = vrow ? p23.x : 0.f, e4 = vrow ? p23.y : 0.f;
        const float e5 = vrow ? p45.x : 0.f, e6 = vrow ? p45.y : 0.f;
        const float eL = __shfl_up(e6, 1);
        const float eR = __shfl_down(e1, 1);
        const float e0 = (q == 0) ? 0.f : eL;
        const float e7 = (q == 7) ? 0.f : eR;
        const v2f A0 = {e0, e1}, A1 = {e2, e3}, A2 = {e4, e5};
        const v2f B0 = {e1, e2}, B1 = {e3, e4}, B2 = {e5, e6};
        const v2f C2 = {e6, e7};
        const int kb = (dy + 1)*3 + (dz + 1);
        const float w0 = Wc[kb];
        const float w1 = Wc[9 + kb];
        const float w2 = Wc[18 + kb];
        const v2f w0v = {w0, w0}, w1v = {w1, w1}, w2v = {w2, w2};
        acc[0] = __builtin_elementwise_fma(A0, w0v, acc[0]);
        acc[0] = __builtin_elementwise_fma(B0, w1v, acc[0]);
        acc[0] = __builtin_elementwise_fma(A1, w2v, acc[0]);
        acc[1] = __builtin_elementwise_fma(A1, w0v, acc[1]);
        acc[1] = __builtin_elementwise_fma(B1, w1v, acc[1]);
        acc[1] = __builtin_elementwise_fma(A2, w2v, acc[1]);
        acc[2] = __builtin_elementwise_fma(A2, w0v, acc[2]);
        acc[2] = __builtin_elementwise_fma(B2, w1v, acc[2]);
        acc[2] = __builtin_elementwise_fma(C2, w2v, acc[2]);
      }
    }
  }
  float* pb = pred0 + (size_t)(cg*NB + b)*MVOX + (size_t)z*(YD*XD) + y*XD + x0;
  *(v2f*)(pb)     = acc[0];
  *(v2f*)(pb + 2) = acc[1];
  *(v2f*)(pb + 4) = acc[2];
}

// per-channel 6-delta partial at one voxel, W from global (delta_kernel path)
__device__ __forceinline__ void delta_ch(const float* __restrict__ fc,
                                         const float* __restrict__ Wt,
                                         int c, int x, int y, int z, float part[6]) {
  #pragma unroll
  for (int dz = -1; dz <= 1; ++dz) {
    const int zz = z + dz;
    if (zz < 0 || zz >= ZD) continue;
    #pragma unroll
    for (int dy = -1; dy <= 1; ++dy) {
      const int yy = y + dy;
      if (yy < 0 || yy >= YD) continue;
      const float* rp = fc + (zz*YD + yy)*XD;
      const float e0 = (x > 0)    ? rp[x-1] : 0.f;
      const float e1 = rp[x];
      const float e2 = (x < XD-1) ? rp[x+1] : 0.f;
      const int kb = (dy + 1)*3 + (dz + 1);
      #pragma unroll
      for (int o = 0; o < 6; ++o) {
        const float* Wo = Wt + (size_t)(o + 1)*(CD*27) + c*27;
        part[o] = fmaf(e2, Wo[18 + kb], fmaf(e1, Wo[9 + kb], fmaf(e0, Wo[kb], part[o])));
      }
    }
  }
}

// ---------------- minidelta: dense 6-ch deltas over GT core regions (W in LDS) ----------------
__global__ __launch_bounds__(256) void minidelta(const float* __restrict__ feat_zyx,
                                                 const float* __restrict__ Wt,
                                                 const float* __restrict__ cbias,
                                                 const float* __restrict__ lrt,
                                                 float* __restrict__ dstore) {
  __shared__ float Wl[6*CD*27];
  for (int i = threadIdx.x; i < 6*CD*27; i += 256) Wl[i] = Wt[CD*27 + i];

  const int n = blockIdx.x, slice = blockIdx.y, b = blockIdx.z;
  const int lane = threadIdx.x & 63;
  const int wv = threadIdx.x >> 6;
  const float* g = lrt + (b*NGT + n)*19;
  const float l0 = g[0], l1 = g[1], l2 = g[2];
  const float t0 = g[6], t1 = g[10], t2 = g[14];
  const float r0 = 0.25f*l0 + 1e-4f, r1 = 0.25f*l1 + 1e-4f, r2 = 0.25f*l2 + 1e-4f;
  const int xlo = max(0, (int)ceilf(t0 - r0 - 1e-3f)), xhi = min(XD-1, (int)floorf(t0 + r0 + 1e-3f));
  const int ylo = max(0, (int)ceilf(t1 - r1 - 1e-3f)), yhi = min(YD-1, (int)floorf(t1 + r1 + 1e-3f));
  const int zlo = max(0, (int)ceilf(t2 - r2 - 1e-3f)), zhi = min(ZD-1, (int)floorf(t2 + r2 + 1e-3f));
  const int nx = xhi - xlo + 1, ny = yhi - ylo + 1, nz = zhi - zlo + 1;
  __syncthreads();
  if (nx <= 0 || ny <= 0 || nz <= 0) return;
  const int total = nx * ny * nz;

  const float* fc = feat_zyx + ((size_t)b*CD + lane) * MVOX;
  const float* Wc = Wl + lane*27;
  for (int i = slice*4 + wv; i < total; i += NSLICE*4) {
    const int vx = xlo + (i % nx);
    const int vy = ylo + ((i / nx) % ny);
    const int vz = zlo + (i / (nx * ny));
    float part[6] = {0.f,0.f,0.f,0.f,0.f,0.f};
    #pragma unroll
    for (int dz = -1; dz <= 1; ++dz) {
      const int zz = vz + dz;
      if (zz < 0 || zz >= ZD) continue;
      #pragma unroll
      for (int dy = -1; dy <= 1; ++dy) {
        const int yy = vy + dy;
        if (yy < 0 || yy >= YD) continue;
        const float* rp = fc + (zz*YD + yy)*XD;
        const float e0 = (vx > 0)    ? rp[vx-1] : 0.f;
        const float e1 = rp[vx];
        const float e2 = (vx < XD-1) ? rp[vx+1] : 0.f;
        const int kb = (dy + 1)*3 + (dz + 1);
        #pragma unroll
        for (int o = 0; o < 6; ++o) {
          const float* Wo = Wc + o*(CD*27);
          part[o] = fmaf(e2, Wo[18 + kb], fmaf(e1, Wo[9 + kb], fmaf(e0, Wo[kb], part[o])));
        }
      }
    }
    #pragma unroll
    for (int off = 32; off; off >>= 1) {
      #pragma unroll
      for (int o = 0; o < 6; ++o)
        part[o] += __shfl_down(part[o], off);
    }
    if (lane == 0) {
      const size_t w = (size_t)vz*(YD*XD) + vy*XD + vx;
      #pragma unroll
      for (int o = 0; o < 6; ++o)
        dstore[((size_t)b*6 + o)*MVOX + w] = cbias[1 + o] + part[o];
    }
  }
}

// ---------------- loss + fused log-bin histogram ----------------
template<int GG>
__global__ __launch_bounds__(256) void loss_kernel(const float* __restrict__ pred0,
                                                   const float* __restrict__ dstore,
                                                   const float* __restrict__ cbias,
                                                   const float* __restrict__ lrt,
                                                   const float* __restrict__ scores,
                                                   float* __restrict__ pobj,
                                                   float* __restrict__ partials,
                                                   unsigned* __restrict__ hist1) {
  const int blk = blockIdx.x;
  const int b = blk / BLK_PER_BATCH;
  const int w = (blk % BLK_PER_BATCH) * 256 + threadIdx.x;
  const int z = w / (YD*XD);
  const int rem = w % (YD*XD);
  const int y = rem / XD, x = rem % XD;

  __shared__ float gp[NGT][10];
  __shared__ unsigned lh[NBIN];
  for (int i = threadIdx.x; i < NBIN; i += 256) lh[i] = 0;
  if (threadIdx.x < NGT) {
    const float* g = lrt + (b*NGT + threadIdx.x)*19;
    float l0 = g[0], l1 = g[1], l2 = g[2];
    gp[threadIdx.x][0] = g[6]; gp[threadIdx.x][1] = g[10]; gp[threadIdx.x][2] = g[14];
    gp[threadIdx.x][3] = l0*0.5f + 1e-5f;
    gp[threadIdx.x][4] = l1*0.5f + 1e-5f;
    gp[threadIdx.x][5] = l2*0.5f + 1e-5f;
    gp[threadIdx.x][6] = logf(l0 / ANCH);
    gp[threadIdx.x][7] = logf(l1 / ANCH);
    gp[threadIdx.x][8] = logf(l2 / ANCH);
    gp[threadIdx.x][9] = scores[b*NGT + threadIdx.x];
  }
  __syncthreads();

  float l = cbias[0];
  #pragma unroll
  for (int g = 0; g < GG; ++g)
    l += pred0[(size_t)(g*NB + b)*MVOX + w];

  const float pj = 1.f / (1.f + expf(-l));
  pobj[(size_t)b*MVOX + x*(YD*ZD) + y*ZD + z] = pj;
  atomicAdd(&lh[pjbin(__float_as_uint(pj))], 1u);

  const float fx = (float)x, fy = (float)y, fz = (float)z;
  float cum = 0.f, sneg = 0.f;
  float a[6] = {0.f,0.f,0.f,0.f,0.f,0.f};
  #pragma unroll
  for (int n = 0; n < NGT; ++n) {
    float d0 = gp[n][0] - fx, d1 = gp[n][1] - fy, d2 = gp[n][2] - fz;
    float od = fmaxf(fmaxf(fabsf(d0)/gp[n][3],
                           fabsf(d1)/gp[n][4]),
                           fabsf(d2)/gp[n][5]);
    float sc = gp[n][9];
    float mp = (od < 0.5f) ? sc : 0.f;
    float mn = (od < 0.8f) ? sc : 0.f;
    float prev = (cum >= 0.5f) ? 1.f : 0.f;
    float ctb = mp * (1.f - prev);
    a[0] += ctb * (d0 / ANCH);
    a[1] += ctb * (d1 / ANCH);
    a[2] += ctb * (d2 / ANCH);
    a[3] += ctb * gp[n][6];
    a[4] += ctb * gp[n][7];
    a[5] += ctb * gp[n][8];
    cum += mp; sneg += mn;
  }
  const float pos = (cum  >= 0.5f) ? 1.f : 0.f;
  const float neg = 1.f - ((sneg >= 0.5f) ? 1.f : 0.f);
  const float bce = fmaxf(l, 0.f) - l*pos + log1pf(expf(-fabsf(l)));
  float sl = 0.f;
  if (pos > 0.f) {
    #pragma unroll
    for (int c = 0; c < 6; ++c) {
      float pv = dstore[((size_t)b*6 + c)*MVOX + w];
      float dd = pv - a[c];
      float ad = fabsf(dd);
      sl += (ad < (1.f/9.f)) ? dd*dd*4.5f : (ad - (1.f/18.f));
    }
  }

  float vals5[5] = {bce*pos, bce*neg, pos, neg, sl};
  __shared__ float red[4][5];
  const int lane = threadIdx.x & 63, wid = threadIdx.x >> 6;
  #pragma unroll
  for (int k = 0; k < 5; ++k)
    for (int off = 32; off; off >>= 1)
      vals5[k] += __shfl_down(vals5[k], off);
  if (lane == 0) {
    #pragma unroll
    for (int k = 0; k < 5; ++k) red[wid][k] = vals5[k];
  }
  __syncthreads();
  if (threadIdx.x == 0) {
    #pragma unroll
    for (int k = 0; k < 5; ++k)
      partials[blk*5 + k] = red[0][k] + red[1][k] + red[2][k] + red[3][k];
  }
  for (int i = threadIdx.x; i < NBIN; i += 256) {
    unsigned h = lh[i];
    if (h) atomicAdd(&hist1[b*NBIN + i], h);
  }
}

__device__ __forceinline__ void suffix2048(const unsigned* __restrict__ ghist,
                                           unsigned* sA, unsigned* sB) {
  for (int i = threadIdx.x; i < NBIN; i += 256) sA[i] = ghist[i];
  __syncthreads();
  unsigned* src = sA; unsigned* dst = sB;
  for (int off = 1; off < NBIN; off <<= 1) {
    for (int i = threadIdx.x; i < NBIN; i += 256)
      dst[i] = src[i] + ((i + off < NBIN) ? src[i + off] : 0u);
    __syncthreads();
    unsigned* t = src; src = dst; dst = t;
  }
  if (src != sA) {
    for (int i = threadIdx.x; i < NBIN; i += 256) sA[i] = src[i];
    __syncthreads();
  }
}

// ---------------- collect candidates ----------------
__global__ __launch_bounds__(256) void topk_collect(const float* __restrict__ pobj,
                                                    const unsigned* __restrict__ hist1,
                                                    unsigned* __restrict__ selCnt,
                                                    unsigned long long* __restrict__ cand) {
  const int b = blockIdx.y;
  __shared__ unsigned sA[NBIN], sB[NBIN];
  __shared__ int sT1;
  suffix2048(hist1 + b*NBIN, sA, sB);
  for (int i = threadIdx.x; i < NBIN; i += 256)
    if (sA[i] >= (unsigned)KP && (i == NBIN-1 || sA[i+1] < (unsigned)KP)) sT1 = i;
  __syncthreads();
  const unsigned T1 = (unsigned)sT1;

  const float4* v4 = (const float4*)(pobj + (size_t)b*MVOX);
  #pragma unroll
  for (int r = 0; r < 2; ++r) {
    const int i4 = blockIdx.x*512 + r*256 + threadIdx.x;
    float4 f = v4[i4];
    unsigned kk[4] = {__float_as_uint(f.x), __float_as_uint(f.y),
                      __float_as_uint(f.z), __float_as_uint(f.w)};
    #pragma unroll
    for (int j = 0; j < 4; ++j) {
      const unsigned k = kk[j];
      if (pjbin(k) >= T1) {
        unsigned p = atomicAdd(&selCnt[b], 1u);
        if (p < CANDCAP)
          cand[(size_t)b*CANDCAP + p] =
            ((unsigned long long)(~k) << 32) | (unsigned)(i4*4 + j);
      }
    }
  }
}

// ---------------- sort candidates -> tval/tidx (+ loss finalize) ----------------
__global__ __launch_bounds__(256) void topk_sort(const unsigned* __restrict__ selCnt,
                                                 const unsigned long long* __restrict__ cand,
                                                 float* __restrict__ tval,
                                                 int* __restrict__ tidx,
                                                 const float* __restrict__ partials,
                                                 float* __restrict__ out_loss) {
  const int tid = threadIdx.x;
  if (blockIdx.x == NB) {
    if (tid < 64) {
      double acc[7] = {0,0,0,0,0,0,0};
      for (int i = tid; i < 2*BLK_PER_BATCH; i += 64) {
        const float* p = partials + i*5;
        acc[0] += p[0]; acc[1] += p[1]; acc[2] += p[3];
        if (i < BLK_PER_BATCH) { acc[3] += p[2]; acc[5] += p[4]; }
        else                   { acc[4] += p[2]; acc[6] += p[4]; }
      }
      #pragma unroll
      for (int k = 0; k < 7; ++k)
        for (int off = 32; off; off >>= 1)
          acc[k] += __shfl_down(acc[k], off);
      if (tid == 0) {
        double posg = acc[3] + acc[4];
        double cls_pos = acc[0] / (posg + 1e-6);
        double cls_neg = acc[1] / (acc[2] + 1e-6);
        double loss_prob = 1.5*cls_pos + cls_neg;
        double ps0 = fmax(acc[3], 1.0), ps1 = fmax(acc[4], 1.0);
        double loss_reg = (acc[5]/ps0 + acc[6]/ps1) / (double)NB;
        out_loss[0] = (float)(loss_prob + loss_reg);
      }
    }
    return;
  }
  const int b = blockIdx.x;
  __shared__ unsigned long long comp[CANDCAP];
  const int n = min((int)selCnt[b], CANDCAP);
  int P = 256; while (P < n) P <<= 1;
  for (int i = tid; i < P; i += 256)
    comp[i] = (i < n) ? cand[(size_t)b*CANDCAP + i] : ~0ull;
  __syncthreads();
  for (int k = 2; k <= P; k <<= 1)
    for (int jj = k >> 1; jj > 0; jj >>= 1) {
      for (int i = tid; i < P; i += 256) {
        const int ixj = i ^ jj;
        if (ixj > i) {
          unsigned long long aa = comp[i], cc = comp[ixj];
          bool up = ((i & k) == 0);
          if ((aa > cc) == up) { comp[i] = cc; comp[ixj] = aa; }
        }
      }
      __syncthreads();
    }
  if (tid < KP) {
    unsigned long long cc = comp[tid];
    tidx[b*KP + tid] = (int)(cc & 0xffffffffull);
    tval[b*KP + tid] = __uint_as_float(~(unsigned)(cc >> 32));
  }
}

// ---------------- deltas for the sorted top-128 (one block per candidate) ----------------
__global__ __launch_bounds__(64) void delta_kernel(const int* __restrict__ tidx,
                                                   const float* __restrict__ feat_zyx,
                                                   const float* __restrict__ Wt,
                                                   const float* __restrict__ cbias,
                                                   float* __restrict__ dlBuf) {
  const int j = blockIdx.x, b = blockIdx.y;
  const int c = threadIdx.x;
  const int idx = tidx[b*KP + j];
  const int xi = idx / (YD*ZD), yi = (idx / ZD) % YD, zi = idx % ZD;

  float part[6] = {0.f,0.f,0.f,0.f,0.f,0.f};
  delta_ch(feat_zyx + ((size_t)b*CD + c)*MVOX, Wt, c, xi, yi, zi, part);
  #pragma unroll
  for (int off = 32; off; off >>= 1) {
    #pragma unroll
    for (int o = 0; o < 6; ++o)
      part[o] += __shfl_down(part[o], off);
  }
  if (c == 0) {
    #pragma unroll
    for (int o = 0; o < 6; ++o)
      dlBuf[((size_t)b*KP + j)*6 + o] = cbias[1 + o] + part[o];
  }
}

// ---------------- final: boxes + NMS (wave-parallel greedy) + outputs ----------------
__global__ __launch_bounds__(256) void final_nms(const float* __restrict__ tval,
                                                 const int* __restrict__ tidx,
                                                 const float* __restrict__ dlBuf,
                                                 const float* __restrict__ lrt,
                                                 const float* __restrict__ scores,
                                                 float* __restrict__ out_boxes,
                                                 float* __restrict__ out_scores,
                                                 float* __restrict__ out_keep,
                                                 float* __restrict__ out_ovr) {
  const int b = blockIdx.x, tid = threadIdx.x;
  const int row = tid & 127;
  __shared__ float Bxy[KP][4], Bzx[KP][4];
  __shared__ unsigned long long RowXY[KP][2], RowZX[KP][2];
  __shared__ unsigned long long vmaskS[2], keepXY[2], keepZX[2];
  __shared__ float Gmin[NGT][3], Gmax[NGT][3], Gvol[NGT], Gsc[NGT];

  float val = 0.f, cx=0,cy=0,cz=0,bm0=0,bm1=0,bm2=0,bM0=0,bM1=0,bM2=0;
  bool valid = false;
  if (tid < KP) {
    val = tval[b*KP + row];
    const int idx = tidx[b*KP + row];
    const int xi = idx / (YD*ZD), yi = (idx / ZD) % YD, zi = idx % ZD;
    const float* dl = dlBuf + ((size_t)b*KP + row)*6;
    cx = (float)xi + dl[0]*ANCH; cy = (float)yi + dl[1]*ANCH; cz = (float)zi + dl[2]*ANCH;
    float hx = 0.5f*expf(dl[3])*ANCH, hy = 0.5f*expf(dl[4])*ANCH, hz = 0.5f*expf(dl[5])*ANCH;
    bm0 = cx - hx; bm1 = cy - hy; bm2 = cz - hz;
    bM0 = cx + hx; bM1 = cy + hy; bM2 = cz + hz;
    valid = val > 0.9f;
    float vm0 = valid ? bm0 : 0.f, vm1 = valid ? bm1 : 0.f, vm2 = valid ? bm2 : 0.f;
    float vM0 = valid ? bM0 : 0.f, vM1 = valid ? bM1 : 0.f, vM2 = valid ? bM2 : 0.f;
    Bxy[row][0] = vm1; Bxy[row][1] = vm2; Bxy[row][2] = vM1; Bxy[row][3] = vM2;
    Bzx[row][0] = vm0; Bzx[row][1] = vm2; Bzx[row][2] = vM0; Bzx[row][3] = vM2;
  }
  unsigned long long bal = __ballot(valid);
  if (tid < KP && (tid & 63) == 0) vmaskS[tid >> 6] = bal;
  if (tid < NGT) {
    const float* g = lrt + (b*NGT + tid)*19;
    float l0 = g[0], l1 = g[1], l2 = g[2];
    float R00=g[3],R01=g[4],R02=g[5],  t0=g[6];
    float R10=g[7],R11=g[8],R12=g[9],  t1=g[10];
    float R20=g[11],R21=g[12],R22=g[13],t2=g[14];
    float mn0=1e30f,mn1=1e30f,mn2=1e30f,mx0=-1e30f,mx1=-1e30f,mx2=-1e30f;
    #pragma unroll
    for (int s = 0; s < 8; ++s) {
      float sx = (s & 4) ? 0.5f : -0.5f;
      float sy = (s & 2) ? 0.5f : -0.5f;
      float sz = (s & 1) ? 0.5f : -0.5f;
      float px = sx*l0, py = sy*l1, pz = sz*l2;
      float c0 = R00*px + R01*py + R02*pz + t0;
      float c1 = R10*px + R11*py + R12*pz + t1;
      float c2 = R20*px + R21*py + R22*pz + t2;
      mn0 = fminf(mn0, c0); mx0 = fmaxf(mx0, c0);
      mn1 = fminf(mn1, c1); mx1 = fmaxf(mx1, c1);
      mn2 = fminf(mn2, c2); mx2 = fmaxf(mx2, c2);
    }
    Gmin[tid][0]=mn0; Gmin[tid][1]=mn1; Gmin[tid][2]=mn2;
    Gmax[tid][0]=mx0; Gmax[tid][1]=mx1; Gmax[tid][2]=mx2;
    Gvol[tid] = (mx0-mn0)*(mx1-mn1)*(mx2-mn2);
    Gsc[tid] = (scores[b*NGT + tid] > 0.f) ? 1.f : 0.f;
  }
  __syncthreads();

  {
    const float (*Btab)[4] = (tid < KP) ? Bxy : Bzx;
    const float a0 = Btab[row][0], a1 = Btab[row][1];
    const float a2 = Btab[row][2], a3 = Btab[row][3];
    const float areaA = (a2 - a0)*(a3 - a1);
    unsigned long long r0 = 0, r1 = 0;
    for (int i = 0; i < KP; ++i) {
      float lo1 = fmaxf(a0, Btab[i][0]), lo2 = fmaxf(a1, Btab[i][1]);
      float hi1 = fminf(a2, Btab[i][2]), hi2 = fminf(a3, Btab[i][3]);
      float inter = fmaxf(hi1 - lo1, 0.f) * fmaxf(hi2 - lo2, 0.f);
      float areaB = (Btab[i][2]-Btab[i][0])*(Btab[i][3]-Btab[i][1]);
      float iou = inter / (areaA + areaB - inter + 1e-9f);
      if (iou > 0.2f) { if (i < 64) r0 |= 1ull << i; else r1 |= 1ull << (i-64); }
    }
    if (tid < KP) { RowXY[row][0] = r0; RowXY[row][1] = r1; }
    else          { RowZX[row][0] = r0; RowZX[row][1] = r1; }
  }
  __syncthreads();

  const int wv = tid >> 6;
  if (wv == 0 || wv == 2) {
    const int l = tid & 63;
    const unsigned long long (*Rt)[2] = (wv == 0) ? RowXY : RowZX;
    const unsigned long long rA0 = Rt[l][0],     rA1 = Rt[l][1];
    const unsigned long long rB0 = Rt[l+64][0],  rB1 = Rt[l+64][1];
    const unsigned long long vm0 = vmaskS[0], vm1 = vmaskS[1];
    unsigned long long k0 = 0, k1 = 0;
    for (int i = 0; i < KP; ++i) {
      const int src = i & 63;
      const unsigned long long q0 = shfl_u64((i < 64) ? rA0 : rB0, src);
      const unsigned long long q1 = shfl_u64((i < 64) ? rA1 : rB1, src);
      const bool vv = (i < 64) ? ((vm0 >> i) & 1ull) : ((vm1 >> (i-64)) & 1ull);
      const bool sup = ((q0 & k0) | (q1 & k1)) != 0ull;
      if (vv && !sup) { if (i < 64) k0 |= 1ull << i; else k1 |= 1ull << (i-64); }
    }
    if (l == 0) {
      if (wv == 0) { keepXY[0] = k0; keepXY[1] = k1; }
      else         { keepZX[0] = k0; keepZX[1] = k1; }
    }
  }
  __syncthreads();

  if (tid < KP) {
    const unsigned long long kk = (row < 64)
      ? ((keepXY[0] | keepZX[0]) >> row)
      : ((keepXY[1] | keepZX[1]) >> (row - 64));
    const bool keep = kk & 1ull;
    const float kf = keep ? 1.f : 0.f;
    float* ob = out_boxes + ((size_t)b*KP + row)*6;
    ob[0] = cx*kf; ob[1] = cy*kf; ob[2] = cz*kf;
    ob[3] = (bM0-bm0)*kf; ob[4] = (bM1-bm1)*kf; ob[5] = (bM2-bm2)*kf;
    out_scores[b*KP + row] = val * kf;
    out_keep[b*KP + row] = kf;
    const float volA = (bM0-bm0)*(bM1-bm1)*(bM2-bm2);
    for (int n2 = 0; n2 < NGT; ++n2) {
      float lo0 = fmaxf(bm0, Gmin[n2][0]), lo1 = fmaxf(bm1, Gmin[n2][1]), lo2 = fmaxf(bm2, Gmin[n2][2]);
      float hi0 = fminf(bM0, Gmax[n2][0]), hi1 = fminf(bM1, Gmax[n2][1]), hi2 = fminf(bM2, Gmax[n2][2]);
      float inter = fmaxf(hi0-lo0, 0.f)*fmaxf(hi1-lo1, 0.f)*fmaxf(hi2-lo2, 0.f);
      float iou3 = inter / (volA + Gvol[n2] - inter + 1e-9f);
      out_ovr[((size_t)b*KP + row)*NGT + n2] = iou3 * kf * Gsc[n2];
    }
  }
}

extern "C" void kernel_launch(void* const* d_in, const int* in_sizes, int n_in,
                              void* d_out, int out_size, void* d_ws, size_t ws_size,
                              hipStream_t stream) {
  const float* lrt    = (const float*)d_in[0];
  const float* scores = (const float*)d_in[1];
  const float* feat   = (const float*)d_in[2];
  const float* Wt     = (const float*)d_in[3];
  const float* cbias  = (const float*)d_in[4];

  float* out = (float*)d_out;
  float* out_loss   = out;
  float* out_pobj   = out + 1;
  float* out_boxes  = out_pobj + NB*MVOX;
  float* out_scores = out_boxes + NB*KP*6;
  float* out_keep   = out_scores + NB*KP;
  float* out_ovr    = out_keep + NB*KP;

  const size_t per = (size_t)NB*MVOX;
  const size_t tail_f = (size_t)NB*6*MVOX + 2*(size_t)NB*CANDCAP + NB*NBIN + NB
                      + 2*BLK_PER_BATCH*5 + NB*KP*2 + NB*KP*6 + 64;
  int G = 16;
  while (G > 1 && ws_size < (per*(size_t)G + tail_f)*sizeof(float)) G >>= 1;

  float*              pred0    = (float*)d_ws;
  float*              dstore   = pred0 + per*(size_t)G;
  unsigned long long* cand     = (unsigned long long*)(dstore + (size_t)NB*6*MVOX);
  unsigned*           hist1    = (unsigned*)(cand + (size_t)NB*CANDCAP);
  unsigned*           selCnt   = hist1 + NB*NBIN;
  float*              partials = (float*)(selCnt + NB);
  float*              tval     = partials + 2*BLK_PER_BATCH*5;
  int*                tidx     = (int*)(tval + NB*KP);
  float*              dlBuf    = (float*)(tidx + NB*KP);
  const int zeroN = NB*NBIN + NB;

  dim3 cgrid(12, 4, NB*G);
  dim3 cblk(384);
  if (G == 16)     conv_kernel<4><<<cgrid, cblk, 0, stream>>>(feat, Wt, pred0, hist1, zeroN);
  else if (G == 8) conv_kernel<8><<<cgrid, cblk, 0, stream>>>(feat, Wt, pred0, hist1, zeroN);
  else if (G == 4) conv_kernel<16><<<cgrid, cblk, 0, stream>>>(feat, Wt, pred0, hist1, zeroN);
  else if (G == 2) conv_kernel<32><<<cgrid, cblk, 0, stream>>>(feat, Wt, pred0, hist1, zeroN);
  else             conv_kernel<64><<<cgrid, cblk, 0, stream>>>(feat, Wt, pred0, hist1, zeroN);

  minidelta<<<dim3(NGT, NSLICE, NB), dim3(256), 0, stream>>>(feat, Wt, cbias, lrt, dstore);

  if (G == 16)
    loss_kernel<16><<<dim3(2*BLK_PER_BATCH), dim3(256), 0, stream>>>(pred0, dstore, cbias, lrt,
                                                                     scores, out_pobj, partials, hist1);
  else if (G == 8)
    loss_kernel<8><<<dim3(2*BLK_PER_BATCH), dim3(256), 0, stream>>>(pred0, dstore, cbias, lrt,
                                                                    scores, out_pobj, partials, hist1);
  else if (G == 4)
    loss_kernel<4><<<dim3(2*BLK_PER_BATCH), dim3(256), 0, stream>>>(pred0, dstore, cbias, lrt,
                                                                    scores, out_pobj, partials, hist1);
  else if (G == 2)
    loss_kernel<2><<<dim3(2*BLK_PER_BATCH), dim3(256), 0, stream>>>(pred0, dstore, cbias, lrt,
                                                                    scores, out_pobj, partials, hist1);
  else
    loss_kernel<1><<<dim3(2*BLK_PER_BATCH), dim3(256), 0, stream>>>(pred0, dstore, cbias, lrt,
                                                                    scores, out_pobj, partials, hist1);

  topk_collect<<<dim3(54, NB), dim3(256), 0, stream>>>(out_pobj, hist1, selCnt, cand);
  topk_sort<<<dim3(NB + 1), dim3(256), 0, stream>>>(selCnt, cand, tval, tidx, partials, out_loss);
  delta_kernel<<<dim3(KP, NB), dim3(64), 0, stream>>>(tidx, feat, Wt, cbias, dlBuf);
  final_nms<<<dim3(NB), dim3(256), 0, stream>>>(tval, tidx, dlBuf, lrt, scores,
                                                out_boxes, out_scores, out_keep, out_ovr);
}

// Round 24
// 136.718 us; speedup vs baseline: 1.0412x; 1.0412x over previous
//
#include <hip/hip_runtime.h>
#include <math.h>

#define XD 48
#define YD 48
#define ZD 48
#define CD 64
#define NGT 10
#define NB 2
#define KP 128
#define MVOX (XD*YD*ZD)   // 110592
#define ANCH 12.0f
#define BLK_PER_BATCH 432 // MVOX/256

#define NBIN 2048
#define CANDCAP 4096
#define NSLICE 32

typedef float v2f __attribute__((ext_vector_type(2)));

__device__ __forceinline__ unsigned pjbin(unsigned pbits) {
  unsigned d = 0x3F800000u - pbits;
  if (d == 0u) return 2047u;
  int msb = 31 - __clz(d);
  unsigned frac = (msb >= 6) ? ((d >> (msb - 6)) & 63u) : ((d << (6 - msb)) & 63u);
  unsigned bin = ((unsigned)msb << 6) | frac;
  return 2047u - bin;
}

__device__ __forceinline__ unsigned long long shfl_u64(unsigned long long v, int src) {
  int lo = __shfl((int)(unsigned)(v & 0xffffffffull), src);
  int hi = __shfl((int)(unsigned)(v >> 32), src);
  return ((unsigned long long)(unsigned)hi << 32) | (unsigned)lo;
}

// ---------------- conv: channel-0 (logit) only; block covers 4 z-planes for L1 halo reuse ----------------
// block 384 = (8 xseg) x (12 y) x (4 z); grid (12, 4, NB*G)
template<int CPG>
__global__ __launch_bounds__(384) void conv_kernel(const float* __restrict__ feat_zyx,
                                                   const float* __restrict__ Wt,
                                                   float* __restrict__ pred0,
                                                   unsigned* __restrict__ zeroBuf,
                                                   int zeroN) {
  const int t = threadIdx.x;
  const int q = t & 7;                    // x-segment 0..7
  const int yloc = (t >> 3) % 12;
  const int zloc = (t >> 3) / 12;         // 0..3
  const int y = blockIdx.y*12 + yloc;
  const int z = blockIdx.x*4 + zloc;
  const int cg = blockIdx.z >> 1;
  const int b  = blockIdx.z & 1;
  const int c0 = cg * CPG;
  const int x0 = q * 6;

  if (blockIdx.x == 0 && blockIdx.y == 0 && blockIdx.z == 0)
    for (int i = t; i < zeroN; i += 384) zeroBuf[i] = 0u;

  v2f acc[3];
  #pragma unroll
  for (int j = 0; j < 3; ++j) acc[j] = (v2f){0.f, 0.f};

  const float* fb = feat_zyx + ((size_t)b*CD + c0) * MVOX;
  for (int cc = 0; cc < CPG; ++cc) {
    const float* fc = fb + (size_t)cc * MVOX;
    const float* Wc = Wt + (c0 + cc) * 27;
    #pragma unroll
    for (int dz = -1; dz <= 1; ++dz) {
      const int zz = z + dz;
      if (zz < 0 || zz >= ZD) continue;
      #pragma unroll
      for (int dy = -1; dy <= 1; ++dy) {
        const int yy = y + dy;
        const bool vrow = (yy >= 0 && yy < YD);
        const float* rp = fc + (zz*YD + (vrow ? yy : 0))*XD + x0;
        float2 p01 = *(const float2*)(rp);
        float2 p23 = *(const float2*)(rp + 2);
        float2 p45 = *(const float2*)(rp + 4);
        const float e1 = vrow ? p01.x : 0.f, e2 = vrow ? p01.y : 0.f;
        const float e3 = vrow ? p23.x : 0.f, e4 = vrow ? p23.y : 0.f;
        const float e5 = vrow ? p45.x : 0.f, e6 = vrow ? p45.y : 0.f;
        const float eL = __shfl_up(e6, 1);
        const float eR = __shfl_down(e1, 1);
        const float e0 = (q == 0) ? 0.f : eL;
        const float e7 = (q == 7) ? 0.f : eR;
        const v2f A0 = {e0, e1}, A1 = {e2, e3}, A2 = {e4, e5};
        const v2f B0 = {e1, e2}, B1 = {e3, e4}, B2 = {e5, e6};
        const v2f C2 = {e6, e7};
        const int kb = (dy + 1)*3 + (dz + 1);
        const float w0 = Wc[kb];
        const float w1 = Wc[9 + kb];
        const float w2 = Wc[18 + kb];
        const v2f w0v = {w0, w0}, w1v = {w1, w1}, w2v = {w2, w2};
        acc[0] = __builtin_elementwise_fma(A0, w0v, acc[0]);
        acc[0] = __builtin_elementwise_fma(B0, w1v, acc[0]);
        acc[0] = __builtin_elementwise_fma(A1, w2v, acc[0]);
        acc[1] = __builtin_elementwise_fma(A1, w0v, acc[1]);
        acc[1] = __builtin_elementwise_fma(B1, w1v, acc[1]);
        acc[1] = __builtin_elementwise_fma(A2, w2v, acc[1]);
        acc[2] = __builtin_elementwise_fma(A2, w0v, acc[2]);
        acc[2] = __builtin_elementwise_fma(B2, w1v, acc[2]);
        acc[2] = __builtin_elementwise_fma(C2, w2v, acc[2]);
      }
    }
  }
  float* pb = pred0 + (size_t)(cg*NB + b)*MVOX + (size_t)z*(YD*XD) + y*XD + x0;
  *(v2f*)(pb)     = acc[0];
  *(v2f*)(pb + 2) = acc[1];
  *(v2f*)(pb + 4) = acc[2];
}

// per-channel 6-delta partial at one voxel, W from global (delta_kernel path)
__device__ __forceinline__ void delta_ch(const float* __restrict__ fc,
                                         const float* __restrict__ Wt,
                                         int c, int x, int y, int z, float part[6]) {
  #pragma unroll
  for (int dz = -1; dz <= 1; ++dz) {
    const int zz = z + dz;
    if (zz < 0 || zz >= ZD) continue;
    #pragma unroll
    for (int dy = -1; dy <= 1; ++dy) {
      const int yy = y + dy;
      if (yy < 0 || yy >= YD) continue;
      const float* rp = fc + (zz*YD + yy)*XD;
      const float e0 = (x > 0)    ? rp[x-1] : 0.f;
      const float e1 = rp[x];
      const float e2 = (x < XD-1) ? rp[x+1] : 0.f;
      const int kb = (dy + 1)*3 + (dz + 1);
      #pragma unroll
      for (int o = 0; o < 6; ++o) {
        const float* Wo = Wt + (size_t)(o + 1)*(CD*27) + c*27;
        part[o] = fmaf(e2, Wo[18 + kb], fmaf(e1, Wo[9 + kb], fmaf(e0, Wo[kb], part[o])));
      }
    }
  }
}

// ---------------- minidelta: dense 6-ch deltas over GT core regions (W in LDS) ----------------
__global__ __launch_bounds__(256) void minidelta(const float* __restrict__ feat_zyx,
                                                 const float* __restrict__ Wt,
                                                 const float* __restrict__ cbias,
                                                 const float* __restrict__ lrt,
                                                 float* __restrict__ dstore) {
  __shared__ float Wl[6*CD*27];
  for (int i = threadIdx.x; i < 6*CD*27; i += 256) Wl[i] = Wt[CD*27 + i];

  const int n = blockIdx.x, slice = blockIdx.y, b = blockIdx.z;
  const int lane = threadIdx.x & 63;
  const int wv = threadIdx.x >> 6;
  const float* g = lrt + (b*NGT + n)*19;
  const float l0 = g[0], l1 = g[1], l2 = g[2];
  const float t0 = g[6], t1 = g[10], t2 = g[14];
  const float r0 = 0.25f*l0 + 1e-4f, r1 = 0.25f*l1 + 1e-4f, r2 = 0.25f*l2 + 1e-4f;
  const int xlo = max(0, (int)ceilf(t0 - r0 - 1e-3f)), xhi = min(XD-1, (int)floorf(t0 + r0 + 1e-3f));
  const int ylo = max(0, (int)ceilf(t1 - r1 - 1e-3f)), yhi = min(YD-1, (int)floorf(t1 + r1 + 1e-3f));
  const int zlo = max(0, (int)ceilf(t2 - r2 - 1e-3f)), zhi = min(ZD-1, (int)floorf(t2 + r2 + 1e-3f));
  const int nx = xhi - xlo + 1, ny = yhi - ylo + 1, nz = zhi - zlo + 1;
  __syncthreads();
  if (nx <= 0 || ny <= 0 || nz <= 0) return;
  const int total = nx * ny * nz;

  const float* fc = feat_zyx + ((size_t)b*CD + lane) * MVOX;
  const float* Wc = Wl + lane*27;
  for (int i = slice*4 + wv; i < total; i += NSLICE*4) {
    const int vx = xlo + (i % nx);
    const int vy = ylo + ((i / nx) % ny);
    const int vz = zlo + (i / (nx * ny));
    float part[6] = {0.f,0.f,0.f,0.f,0.f,0.f};
    #pragma unroll
    for (int dz = -1; dz <= 1; ++dz) {
      const int zz = vz + dz;
      if (zz < 0 || zz >= ZD) continue;
      #pragma unroll
      for (int dy = -1; dy <= 1; ++dy) {
        const int yy = vy + dy;
        if (yy < 0 || yy >= YD) continue;
        const float* rp = fc + (zz*YD + yy)*XD;
        const float e0 = (vx > 0)    ? rp[vx-1] : 0.f;
        const float e1 = rp[vx];
        const float e2 = (vx < XD-1) ? rp[vx+1] : 0.f;
        const int kb = (dy + 1)*3 + (dz + 1);
        #pragma unroll
        for (int o = 0; o < 6; ++o) {
          const float* Wo = Wc + o*(CD*27);
          part[o] = fmaf(e2, Wo[18 + kb], fmaf(e1, Wo[9 + kb], fmaf(e0, Wo[kb], part[o])));
        }
      }
    }
    #pragma unroll
    for (int off = 32; off; off >>= 1) {
      #pragma unroll
      for (int o = 0; o < 6; ++o)
        part[o] += __shfl_down(part[o], off);
    }
    if (lane == 0) {
      const size_t w = (size_t)vz*(YD*XD) + vy*XD + vx;
      #pragma unroll
      for (int o = 0; o < 6; ++o)
        dstore[((size_t)b*6 + o)*MVOX + w] = cbias[1 + o] + part[o];
    }
  }
}

// ---------------- loss + fused log-bin histogram ----------------
template<int GG>
__global__ __launch_bounds__(256) void loss_kernel(const float* __restrict__ pred0,
                                                   const float* __restrict__ dstore,
                                                   const float* __restrict__ cbias,
                                                   const float* __restrict__ lrt,
                                                   const float* __restrict__ scores,
                                                   float* __restrict__ pobj,
                                                   float* __restrict__ partials,
                                                   unsigned* __restrict__ hist1) {
  const int blk = blockIdx.x;
  const int b = blk / BLK_PER_BATCH;
  const int w = (blk % BLK_PER_BATCH) * 256 + threadIdx.x;
  const int z = w / (YD*XD);
  const int rem = w % (YD*XD);
  const int y = rem / XD, x = rem % XD;

  __shared__ float gp[NGT][10];
  __shared__ unsigned lh[NBIN];
  for (int i = threadIdx.x; i < NBIN; i += 256) lh[i] = 0;
  if (threadIdx.x < NGT) {
    const float* g = lrt + (b*NGT + threadIdx.x)*19;
    float l0 = g[0], l1 = g[1], l2 = g[2];
    gp[threadIdx.x][0] = g[6]; gp[threadIdx.x][1] = g[10]; gp[threadIdx.x][2] = g[14];
    gp[threadIdx.x][3] = l0*0.5f + 1e-5f;
    gp[threadIdx.x][4] = l1*0.5f + 1e-5f;
    gp[threadIdx.x][5] = l2*0.5f + 1e-5f;
    gp[threadIdx.x][6] = logf(l0 / ANCH);
    gp[threadIdx.x][7] = logf(l1 / ANCH);
    gp[threadIdx.x][8] = logf(l2 / ANCH);
    gp[threadIdx.x][9] = scores[b*NGT + threadIdx.x];
  }
  __syncthreads();

  float l = cbias[0];
  #pragma unroll
  for (int g = 0; g < GG; ++g)
    l += pred0[(size_t)(g*NB + b)*MVOX + w];

  const float pj = 1.f / (1.f + expf(-l));
  pobj[(size_t)b*MVOX + x*(YD*ZD) + y*ZD + z] = pj;
  atomicAdd(&lh[pjbin(__float_as_uint(pj))], 1u);

  const float fx = (float)x, fy = (float)y, fz = (float)z;
  float cum = 0.f, sneg = 0.f;
  float a[6] = {0.f,0.f,0.f,0.f,0.f,0.f};
  #pragma unroll
  for (int n = 0; n < NGT; ++n) {
    float d0 = gp[n][0] - fx, d1 = gp[n][1] - fy, d2 = gp[n][2] - fz;
    float od = fmaxf(fmaxf(fabsf(d0)/gp[n][3],
                           fabsf(d1)/gp[n][4]),
                           fabsf(d2)/gp[n][5]);
    float sc = gp[n][9];
    float mp = (od < 0.5f) ? sc : 0.f;
    float mn = (od < 0.8f) ? sc : 0.f;
    float prev = (cum >= 0.5f) ? 1.f : 0.f;
    float ctb = mp * (1.f - prev);
    a[0] += ctb * (d0 / ANCH);
    a[1] += ctb * (d1 / ANCH);
    a[2] += ctb * (d2 / ANCH);
    a[3] += ctb * gp[n][6];
    a[4] += ctb * gp[n][7];
    a[5] += ctb * gp[n][8];
    cum += mp; sneg += mn;
  }
  const float pos = (cum  >= 0.5f) ? 1.f : 0.f;
  const float neg = 1.f - ((sneg >= 0.5f) ? 1.f : 0.f);
  const float bce = fmaxf(l, 0.f) - l*pos + log1pf(expf(-fabsf(l)));
  float sl = 0.f;
  if (pos > 0.f) {
    #pragma unroll
    for (int c = 0; c < 6; ++c) {
      float pv = dstore[((size_t)b*6 + c)*MVOX + w];
      float dd = pv - a[c];
      float ad = fabsf(dd);
      sl += (ad < (1.f/9.f)) ? dd*dd*4.5f : (ad - (1.f/18.f));
    }
  }

  float vals5[5] = {bce*pos, bce*neg, pos, neg, sl};
  __shared__ float red[4][5];
  const int lane = threadIdx.x & 63, wid = threadIdx.x >> 6;
  #pragma unroll
  for (int k = 0; k < 5; ++k)
    for (int off = 32; off; off >>= 1)
      vals5[k] += __shfl_down(vals5[k], off);
  if (lane == 0) {
    #pragma unroll
    for (int k = 0; k < 5; ++k) red[wid][k] = vals5[k];
  }
  __syncthreads();
  if (threadIdx.x == 0) {
    #pragma unroll
    for (int k = 0; k < 5; ++k)
      partials[blk*5 + k] = red[0][k] + red[1][k] + red[2][k] + red[3][k];
  }
  for (int i = threadIdx.x; i < NBIN; i += 256) {
    unsigned h = lh[i];
    if (h) atomicAdd(&hist1[b*NBIN + i], h);
  }
}

__device__ __forceinline__ void suffix2048(const unsigned* __restrict__ ghist,
                                           unsigned* sA, unsigned* sB) {
  for (int i = threadIdx.x; i < NBIN; i += 256) sA[i] = ghist[i];
  __syncthreads();
  unsigned* src = sA; unsigned* dst = sB;
  for (int off = 1; off < NBIN; off <<= 1) {
    for (int i = threadIdx.x; i < NBIN; i += 256)
      dst[i] = src[i] + ((i + off < NBIN) ? src[i + off] : 0u);
    __syncthreads();
    unsigned* t = src; src = dst; dst = t;
  }
  if (src != sA) {
    for (int i = threadIdx.x; i < NBIN; i += 256) sA[i] = src[i];
    __syncthreads();
  }
}

// ---------------- collect candidates ----------------
__global__ __launch_bounds__(256) void topk_collect(const float* __restrict__ pobj,
                                                    const unsigned* __restrict__ hist1,
                                                    unsigned* __restrict__ selCnt,
                                                    unsigned long long* __restrict__ cand) {
  const int b = blockIdx.y;
  __shared__ unsigned sA[NBIN], sB[NBIN];
  __shared__ int sT1;
  suffix2048(hist1 + b*NBIN, sA, sB);
  for (int i = threadIdx.x; i < NBIN; i += 256)
    if (sA[i] >= (unsigned)KP && (i == NBIN-1 || sA[i+1] < (unsigned)KP)) sT1 = i;
  __syncthreads();
  const unsigned T1 = (unsigned)sT1;

  const float4* v4 = (const float4*)(pobj + (size_t)b*MVOX);
  #pragma unroll
  for (int r = 0; r < 2; ++r) {
    const int i4 = blockIdx.x*512 + r*256 + threadIdx.x;
    float4 f = v4[i4];
    unsigned kk[4] = {__float_as_uint(f.x), __float_as_uint(f.y),
                      __float_as_uint(f.z), __float_as_uint(f.w)};
    #pragma unroll
    for (int j = 0; j < 4; ++j) {
      const unsigned k = kk[j];
      if (pjbin(k) >= T1) {
        unsigned p = atomicAdd(&selCnt[b], 1u);
        if (p < CANDCAP)
          cand[(size_t)b*CANDCAP + p] =
            ((unsigned long long)(~k) << 32) | (unsigned)(i4*4 + j);
      }
    }
  }
}

// ---------------- sort candidates -> tval/tidx (+ loss finalize) ----------------
__global__ __launch_bounds__(256) void topk_sort(const unsigned* __restrict__ selCnt,
                                                 const unsigned long long* __restrict__ cand,
                                                 float* __restrict__ tval,
                                                 int* __restrict__ tidx,
                                                 const float* __restrict__ partials,
                                                 float* __restrict__ out_loss) {
  const int tid = threadIdx.x;
  if (blockIdx.x == NB) {
    if (tid < 64) {
      double acc[7] = {0,0,0,0,0,0,0};
      for (int i = tid; i < 2*BLK_PER_BATCH; i += 64) {
        const float* p = partials + i*5;
        acc[0] += p[0]; acc[1] += p[1]; acc[2] += p[3];
        if (i < BLK_PER_BATCH) { acc[3] += p[2]; acc[5] += p[4]; }
        else                   { acc[4] += p[2]; acc[6] += p[4]; }
      }
      #pragma unroll
      for (int k = 0; k < 7; ++k)
        for (int off = 32; off; off >>= 1)
          acc[k] += __shfl_down(acc[k], off);
      if (tid == 0) {
        double posg = acc[3] + acc[4];
        double cls_pos = acc[0] / (posg + 1e-6);
        double cls_neg = acc[1] / (acc[2] + 1e-6);
        double loss_prob = 1.5*cls_pos + cls_neg;
        double ps0 = fmax(acc[3], 1.0), ps1 = fmax(acc[4], 1.0);
        double loss_reg = (acc[5]/ps0 + acc[6]/ps1) / (double)NB;
        out_loss[0] = (float)(loss_prob + loss_reg);
      }
    }
    return;
  }
  const int b = blockIdx.x;
  __shared__ unsigned long long comp[CANDCAP];
  const int n = min((int)selCnt[b], CANDCAP);
  int P = 256; while (P < n) P <<= 1;
  for (int i = tid; i < P; i += 256)
    comp[i] = (i < n) ? cand[(size_t)b*CANDCAP + i] : ~0ull;
  __syncthreads();
  for (int k = 2; k <= P; k <<= 1)
    for (int jj = k >> 1; jj > 0; jj >>= 1) {
      for (int i = tid; i < P; i += 256) {
        const int ixj = i ^ jj;
        if (ixj > i) {
          unsigned long long aa = comp[i], cc = comp[ixj];
          bool up = ((i & k) == 0);
          if ((aa > cc) == up) { comp[i] = cc; comp[ixj] = aa; }
        }
      }
      __syncthreads();
    }
  if (tid < KP) {
    unsigned long long cc = comp[tid];
    tidx[b*KP + tid] = (int)(cc & 0xffffffffull);
    tval[b*KP + tid] = __uint_as_float(~(unsigned)(cc >> 32));
  }
}

// ---------------- deltas for the sorted top-128 (one block per candidate) ----------------
__global__ __launch_bounds__(64) void delta_kernel(const int* __restrict__ tidx,
                                                   const float* __restrict__ feat_zyx,
                                                   const float* __restrict__ Wt,
                                                   const float* __restrict__ cbias,
                                                   float* __restrict__ dlBuf) {
  const int j = blockIdx.x, b = blockIdx.y;
  const int c = threadIdx.x;
  const int idx = tidx[b*KP + j];
  const int xi = idx / (YD*ZD), yi = (idx / ZD) % YD, zi = idx % ZD;

  float part[6] = {0.f,0.f,0.f,0.f,0.f,0.f};
  delta_ch(feat_zyx + ((size_t)b*CD + c)*MVOX, Wt, c, xi, yi, zi, part);
  #pragma unroll
  for (int off = 32; off; off >>= 1) {
    #pragma unroll
    for (int o = 0; o < 6; ++o)
      part[o] += __shfl_down(part[o], off);
  }
  if (c == 0) {
    #pragma unroll
    for (int o = 0; o < 6; ++o)
      dlBuf[((size_t)b*KP + j)*6 + o] = cbias[1 + o] + part[o];
  }
}

// ---------------- final: boxes + NMS (wave-parallel greedy) + outputs ----------------
__global__ __launch_bounds__(256) void final_nms(const float* __restrict__ tval,
                                                 const int* __restrict__ tidx,
                                                 const float* __restrict__ dlBuf,
                                                 const float* __restrict__ lrt,
                                                 const float* __restrict__ scores,
                                                 float* __restrict__ out_boxes,
                                                 float* __restrict__ out_scores,
                                                 float* __restrict__ out_keep,
                                                 float* __restrict__ out_ovr) {
  const int b = blockIdx.x, tid = threadIdx.x;
  const int row = tid & 127;
  __shared__ float Bxy[KP][4], Bzx[KP][4];
  __shared__ unsigned long long RowXY[KP][2], RowZX[KP][2];
  __shared__ unsigned long long vmaskS[2], keepXY[2], keepZX[2];
  __shared__ float Gmin[NGT][3], Gmax[NGT][3], Gvol[NGT], Gsc[NGT];

  float val = 0.f, cx=0,cy=0,cz=0,bm0=0,bm1=0,bm2=0,bM0=0,bM1=0,bM2=0;
  bool valid = false;
  if (tid < KP) {
    val = tval[b*KP + row];
    const int idx = tidx[b*KP + row];
    const int xi = idx / (YD*ZD), yi = (idx / ZD) % YD, zi = idx % ZD;
    const float* dl = dlBuf + ((size_t)b*KP + row)*6;
    cx = (float)xi + dl[0]*ANCH; cy = (float)yi + dl[1]*ANCH; cz = (float)zi + dl[2]*ANCH;
    float hx = 0.5f*expf(dl[3])*ANCH, hy = 0.5f*expf(dl[4])*ANCH, hz = 0.5f*expf(dl[5])*ANCH;
    bm0 = cx - hx; bm1 = cy - hy; bm2 = cz - hz;
    bM0 = cx + hx; bM1 = cy + hy; bM2 = cz + hz;
    valid = val > 0.9f;
    float vm0 = valid ? bm0 : 0.f, vm1 = valid ? bm1 : 0.f, vm2 = valid ? bm2 : 0.f;
    float vM0 = valid ? bM0 : 0.f, vM1 = valid ? bM1 : 0.f, vM2 = valid ? bM2 : 0.f;
    Bxy[row][0] = vm1; Bxy[row][1] = vm2; Bxy[row][2] = vM1; Bxy[row][3] = vM2;
    Bzx[row][0] = vm0; Bzx[row][1] = vm2; Bzx[row][2] = vM0; Bzx[row][3] = vM2;
  }
  unsigned long long bal = __ballot(valid);
  if (tid < KP && (tid & 63) == 0) vmaskS[tid >> 6] = bal;
  if (tid < NGT) {
    const float* g = lrt + (b*NGT + tid)*19;
    float l0 = g[0], l1 = g[1], l2 = g[2];
    float R00=g[3],R01=g[4],R02=g[5],  t0=g[6];
    float R10=g[7],R11=g[8],R12=g[9],  t1=g[10];
    float R20=g[11],R21=g[12],R22=g[13],t2=g[14];
    float mn0=1e30f,mn1=1e30f,mn2=1e30f,mx0=-1e30f,mx1=-1e30f,mx2=-1e30f;
    #pragma unroll
    for (int s = 0; s < 8; ++s) {
      float sx = (s & 4) ? 0.5f : -0.5f;
      float sy = (s & 2) ? 0.5f : -0.5f;
      float sz = (s & 1) ? 0.5f : -0.5f;
      float px = sx*l0, py = sy*l1, pz = sz*l2;
      float c0 = R00*px + R01*py + R02*pz + t0;
      float c1 = R10*px + R11*py + R12*pz + t1;
      float c2 = R20*px + R21*py + R22*pz + t2;
      mn0 = fminf(mn0, c0); mx0 = fmaxf(mx0, c0);
      mn1 = fminf(mn1, c1); mx1 = fmaxf(mx1, c1);
      mn2 = fminf(mn2, c2); mx2 = fmaxf(mx2, c2);
    }
    Gmin[tid][0]=mn0; Gmin[tid][1]=mn1; Gmin[tid][2]=mn2;
    Gmax[tid][0]=mx0; Gmax[tid][1]=mx1; Gmax[tid][2]=mx2;
    Gvol[tid] = (mx0-mn0)*(mx1-mn1)*(mx2-mn2);
    Gsc[tid] = (scores[b*NGT + tid] > 0.f) ? 1.f : 0.f;
  }
  __syncthreads();

  {
    const float (*Btab)[4] = (tid < KP) ? Bxy : Bzx;
    const float a0 = Btab[row][0], a1 = Btab[row][1];
    const float a2 = Btab[row][2], a3 = Btab[row][3];
    const float areaA = (a2 - a0)*(a3 - a1);
    unsigned long long r0 = 0, r1 = 0;
    for (int i = 0; i < KP; ++i) {
      float lo1 = fmaxf(a0, Btab[i][0]), lo2 = fmaxf(a1, Btab[i][1]);
      float hi1 = fminf(a2, Btab[i][2]), hi2 = fminf(a3, Btab[i][3]);
      float inter = fmaxf(hi1 - lo1, 0.f) * fmaxf(hi2 - lo2, 0.f);
      float areaB = (Btab[i][2]-Btab[i][0])*(Btab[i][3]-Btab[i][1]);
      float iou = inter / (areaA + areaB - inter + 1e-9f);
      if (iou > 0.2f) { if (i < 64) r0 |= 1ull << i; else r1 |= 1ull << (i-64); }
    }
    if (tid < KP) { RowXY[row][0] = r0; RowXY[row][1] = r1; }
    else          { RowZX[row][0] = r0; RowZX[row][1] = r1; }
  }
  __syncthreads();

  const int wv = tid >> 6;
  if (wv == 0 || wv == 2) {
    const int l = tid & 63;
    const unsigned long long (*Rt)[2] = (wv == 0) ? RowXY : RowZX;
    const unsigned long long rA0 = Rt[l][0],     rA1 = Rt[l][1];
    const unsigned long long rB0 = Rt[l+64][0],  rB1 = Rt[l+64][1];
    const unsigned long long vm0 = vmaskS[0], vm1 = vmaskS[1];
    unsigned long long k0 = 0, k1 = 0;
    for (int i = 0; i < KP; ++i) {
      const int src = i & 63;
      const unsigned long long q0 = shfl_u64((i < 64) ? rA0 : rB0, src);
      const unsigned long long q1 = shfl_u64((i < 64) ? rA1 : rB1, src);
      const bool vv = (i < 64) ? ((vm0 >> i) & 1ull) : ((vm1 >> (i-64)) & 1ull);
      const bool sup = ((q0 & k0) | (q1 & k1)) != 0ull;
      if (vv && !sup) { if (i < 64) k0 |= 1ull << i; else k1 |= 1ull << (i-64); }
    }
    if (l == 0) {
      if (wv == 0) { keepXY[0] = k0; keepXY[1] = k1; }
      else         { keepZX[0] = k0; keepZX[1] = k1; }
    }
  }
  __syncthreads();

  if (tid < KP) {
    const unsigned long long kk = (row < 64)
      ? ((keepXY[0] | keepZX[0]) >> row)
      : ((keepXY[1] | keepZX[1]) >> (row - 64));
    const bool keep = kk & 1ull;
    const float kf = keep ? 1.f : 0.f;
    float* ob = out_boxes + ((size_t)b*KP + row)*6;
    ob[0] = cx*kf; ob[1] = cy*kf; ob[2] = cz*kf;
    ob[3] = (bM0-bm0)*kf; ob[4] = (bM1-bm1)*kf; ob[5] = (bM2-bm2)*kf;
    out_scores[b*KP + row] = val * kf;
    out_keep[b*KP + row] = kf;
    const float volA = (bM0-bm0)*(bM1-bm1)*(bM2-bm2);
    for (int n2 = 0; n2 < NGT; ++n2) {
      float lo0 = fmaxf(bm0, Gmin[n2][0]), lo1 = fmaxf(bm1, Gmin[n2][1]), lo2 = fmaxf(bm2, Gmin[n2][2]);
      float hi0 = fminf(bM0, Gmax[n2][0]), hi1 = fminf(bM1, Gmax[n2][1]), hi2 = fminf(bM2, Gmax[n2][2]);
      float inter = fmaxf(hi0-lo0, 0.f)*fmaxf(hi1-lo1, 0.f)*fmaxf(hi2-lo2, 0.f);
      float iou3 = inter / (volA + Gvol[n2] - inter + 1e-9f);
      out_ovr[((size_t)b*KP + row)*NGT + n2] = iou3 * kf * Gsc[n2];
    }
  }
}

extern "C" void kernel_launch(void* const* d_in, const int* in_sizes, int n_in,
                              void* d_out, int out_size, void* d_ws, size_t ws_size,
                              hipStream_t stream) {
  const float* lrt    = (const float*)d_in[0];
  const float* scores = (const float*)d_in[1];
  const float* feat   = (const float*)d_in[2];
  const float* Wt     = (const float*)d_in[3];
  const float* cbias  = (const float*)d_in[4];

  float* out = (float*)d_out;
  float* out_loss   = out;
  float* out_pobj   = out + 1;
  float* out_boxes  = out_pobj + NB*MVOX;
  float* out_scores = out_boxes + NB*KP*6;
  float* out_keep   = out_scores + NB*KP;
  float* out_ovr    = out_keep + NB*KP;

  const size_t per = (size_t)NB*MVOX;
  const size_t tail_f = (size_t)NB*6*MVOX + 2*(size_t)NB*CANDCAP + NB*NBIN + NB
                      + 2*BLK_PER_BATCH*5 + NB*KP*2 + NB*KP*6 + 64;
  int G = 8;
  while (G > 1 && ws_size < (per*(size_t)G + tail_f)*sizeof(float)) G >>= 1;

  float*              pred0    = (float*)d_ws;
  float*              dstore   = pred0 + per*(size_t)G;
  unsigned long long* cand     = (unsigned long long*)(dstore + (size_t)NB*6*MVOX);
  unsigned*           hist1    = (unsigned*)(cand + (size_t)NB*CANDCAP);
  unsigned*           selCnt   = hist1 + NB*NBIN;
  float*              partials = (float*)(selCnt + NB);
  float*              tval     = partials + 2*BLK_PER_BATCH*5;
  int*                tidx     = (int*)(tval + NB*KP);
  float*              dlBuf    = (float*)(tidx + NB*KP);
  const int zeroN = NB*NBIN + NB;

  dim3 cgrid(12, 4, NB*G);
  dim3 cblk(384);
  if (G == 8)      conv_kernel<8><<<cgrid, cblk, 0, stream>>>(feat, Wt, pred0, hist1, zeroN);
  else if (G == 4) conv_kernel<16><<<cgrid, cblk, 0, stream>>>(feat, Wt, pred0, hist1, zeroN);
  else if (G == 2) conv_kernel<32><<<cgrid, cblk, 0, stream>>>(feat, Wt, pred0, hist1, zeroN);
  else             conv_kernel<64><<<cgrid, cblk, 0, stream>>>(feat, Wt, pred0, hist1, zeroN);

  minidelta<<<dim3(NGT, NSLICE, NB), dim3(256), 0, stream>>>(feat, Wt, cbias, lrt, dstore);

  if (G == 8)
    loss_kernel<8><<<dim3(2*BLK_PER_BATCH), dim3(256), 0, stream>>>(pred0, dstore, cbias, lrt,
                                                                    scores, out_pobj, partials, hist1);
  else if (G == 4)
    loss_kernel<4><<<dim3(2*BLK_PER_BATCH), dim3(256), 0, stream>>>(pred0, dstore, cbias, lrt,
                                                                    scores, out_pobj, partials, hist1);
  else if (G == 2)
    loss_kernel<2><<<dim3(2*BLK_PER_BATCH), dim3(256), 0, stream>>>(pred0, dstore, cbias, lrt,
                                                                    scores, out_pobj, partials, hist1);
  else
    loss_kernel<1><<<dim3(2*BLK_PER_BATCH), dim3(256), 0, stream>>>(pred0, dstore, cbias, lrt,
                                                                    scores, out_pobj, partials, hist1);

  topk_collect<<<dim3(54, NB), dim3(256), 0, stream>>>(out_pobj, hist1, selCnt, cand);
  topk_sort<<<dim3(NB + 1), dim3(256), 0, stream>>>(selCnt, cand, tval, tidx, partials, out_loss);
  delta_kernel<<<dim3(KP, NB), dim3(64), 0, stream>>>(tidx, feat, Wt, cbias, dlBuf);
  final_nms<<<dim3(NB), dim3(256), 0, stream>>>(tval, tidx, dlBuf, lrt, scores,
                                                out_boxes, out_scores, out_keep, out_ovr);
}